// Round 18
// baseline (119.594 us; speedup 1.0000x reference)
//
#include <hip/hip_runtime.h>
#include <hip/hip_bf16.h>

// ProbSparse attention (Informer). B=4, L=2048, H=8, D=64, S=TOP=40.
constexpr int B = 4, L = 2048, H = 8, D = 64, S = 40, TOP = 40;
constexpr int NMB = B * L;           // 8192 M-blocks: one (b,l) each, all 8 heads

// ================= K_A: compute_M (blocks 0..NMB-1) + vmean partials (next 512) ==========
// (b,l)-centric gather: K[b,ki,:,:] is a contiguous 2KB block covering ALL 8 heads; sample
// indices depend only on l -> one coalesced gather serves 8 heads. ~44us = L2 gather ceiling
// (invariant across 6 access-pattern/depth/occupancy variants, r5-r17).
__global__ __launch_bounds__(256, 8) void kA(const float* __restrict__ Q, const float* __restrict__ K,
                                             const float* __restrict__ V, const int* __restrict__ idx,
                                             float* __restrict__ M, float* __restrict__ Vpart) {
    __shared__ float4 red[256];
    __shared__ float wmax[4][8], wsum[4][8];
    const int t = threadIdx.x;
    if (blockIdx.x < NMB) {
        int n = blockIdx.x;
        int b = n & 3;                                   // xcd = n&7 pins b to 2 XCDs
        int l = ((n >> 2) & 1) * 1024 + (n >> 3);
        int lane = t & 63, w = t >> 6;
        const float* Qb = Q + ((size_t)(b * L + l) << 9);
        const float* Kb = K + ((size_t)(b * L) << 9);
        float4 qa = *(const float4*)(Qb + lane * 4);          // heads 0-3
        float4 qb = *(const float4*)(Qb + 256 + lane * 4);    // heads 4-7
        int ki[10];
        #pragma unroll
        for (int i = 0; i < 10; ++i) ki[i] = idx[l * S + w * 10 + i];   // wave-uniform
        float4 ka[10], kb[10];
        #pragma unroll
        for (int i = 0; i < 10; ++i) {
            const float* kr = Kb + ((size_t)ki[i] << 9);
            ka[i] = *(const float4*)(kr + lane * 4);          // coalesced 1KB per load
            kb[i] = *(const float4*)(kr + 256 + lane * 4);
        }
        float maxa = -3.4e38f, suma = 0.f, maxb = -3.4e38f, sumb = 0.f;
        #pragma unroll
        for (int i = 0; i < 10; ++i) {
            float pa = qa.x * ka[i].x + qa.y * ka[i].y + qa.z * ka[i].z + qa.w * ka[i].w;
            float pb = qb.x * kb[i].x + qb.y * kb[i].y + qb.z * kb[i].z + qb.w * kb[i].w;
            pa += __shfl_xor(pa, 1); pa += __shfl_xor(pa, 2);
            pa += __shfl_xor(pa, 4); pa += __shfl_xor(pa, 8);
            pb += __shfl_xor(pb, 1); pb += __shfl_xor(pb, 2);
            pb += __shfl_xor(pb, 4); pb += __shfl_xor(pb, 8);
            maxa = fmaxf(maxa, pa); suma += pa;
            maxb = fmaxf(maxb, pb); sumb += pb;
        }
        if ((lane & 15) == 0) {
            int g = lane >> 4;
            wmax[w][g] = maxa;     wsum[w][g] = suma;
            wmax[w][g + 4] = maxb; wsum[w][g + 4] = sumb;
        }
        __syncthreads();
        if (t < 8) {
            float mv = wmax[0][t], sv = wsum[0][t];
            #pragma unroll
            for (int ww = 1; ww < 4; ++ww) { mv = fmaxf(mv, wmax[ww][t]); sv += wsum[ww][t]; }
            M[(b * 8 + t) * L + l] = mv - sv * (1.0f / (float)L);
        }
    } else {
        // ---- V mean partials: 512 blocks ----
        int m = blockIdx.x - NMB;                       // NMB % 8 == 0
        int xcd = m & 7, slot = m >> 3;                 // slot in [0,64)
        int bh = xcd * 4 + (slot & 3);
        int chunk = slot >> 2;                          // [0,16)
        int b = bh >> 3, h = bh & 7;
        int d4 = t & 15, rr = t >> 4;
        int l0 = chunk * 128;
        float4 acc = make_float4(0.f, 0.f, 0.f, 0.f);
        #pragma unroll
        for (int s = 0; s < 8; ++s) {
            int l = l0 + rr + s * 16;
            float4 v = *(const float4*)&V[(((b * L + l) * H + h) << 6) + d4 * 4];
            acc.x += v.x; acc.y += v.y; acc.z += v.z; acc.w += v.w;
        }
        red[t] = acc;
        __syncthreads();
        #pragma unroll
        for (int off = 8; off > 0; off >>= 1) {
            if (rr < off) {
                float4 o = red[t + off * 16];
                red[t].x += o.x; red[t].y += o.y; red[t].z += o.z; red[t].w += o.w;
            }
            __syncthreads();
        }
        if (rr == 0) *(float4*)&Vpart[(bh * 16 + chunk) * 64 + d4 * 4] = red[t];
    }
}

// ================= K_B: top-40 (blocks 0..31, one per bh, 8 vals/thread in regs)
//                        + mean finalize (blocks 32..39) =============================
__global__ __launch_bounds__(256) void kB(const float* __restrict__ M, const float* __restrict__ Vpart,
                                          int* __restrict__ Mtop, float* __restrict__ mean) {
    const int t = threadIdx.x;
    if (blockIdx.x < 32) {
        const int bh = blockIdx.x;
        const int lane = t & 63, wid = t >> 6;
        float v[8];                               // 8 regs, statically indexed everywhere
        #pragma unroll
        for (int j = 0; j < 8; ++j) v[j] = M[bh * L + j * 256 + t];
        float bv = v[0]; int bj = 0;              // cached per-thread argmax
        #pragma unroll
        for (int j = 1; j < 8; ++j) if (v[j] > bv) { bv = v[j]; bj = j; }
        __shared__ float swv[4];
        __shared__ int   swi[4];
        __shared__ int   winS;
        for (int it = 0; it < TOP; ++it) {
            float cv = bv; int ci = bj * 256 + t;      // global index l = j*256 + t
            #pragma unroll
            for (int m = 1; m < 64; m <<= 1) {
                float ov = __shfl_xor(cv, m); int oi = __shfl_xor(ci, m);
                if (ov > cv || (ov == cv && oi < ci)) { cv = ov; ci = oi; }
            }
            if (lane == 0) { swv[wid] = cv; swi[wid] = ci; }
            __syncthreads();
            if (t == 0) {
                float fv = swv[0]; int fi = swi[0];
                #pragma unroll
                for (int w = 1; w < 4; ++w)
                    if (swv[w] > fv || (swv[w] == fv && swi[w] < fi)) { fv = swv[w]; fi = swi[w]; }
                Mtop[bh * TOP + it] = fi;
                winS = fi;
            }
            __syncthreads();
            const int wl = winS;
            if ((wl & 255) == t) {                 // owner thread: kill + rescan 8 (static)
                if ((wl >> 8) == 0) v[0] = -3.4e38f;
                if ((wl >> 8) == 1) v[1] = -3.4e38f;
                if ((wl >> 8) == 2) v[2] = -3.4e38f;
                if ((wl >> 8) == 3) v[3] = -3.4e38f;
                if ((wl >> 8) == 4) v[4] = -3.4e38f;
                if ((wl >> 8) == 5) v[5] = -3.4e38f;
                if ((wl >> 8) == 6) v[6] = -3.4e38f;
                if ((wl >> 8) == 7) v[7] = -3.4e38f;
                bv = v[0]; bj = 0;
                #pragma unroll
                for (int j = 1; j < 8; ++j) if (v[j] > bv) { bv = v[j]; bj = j; }
            }
        }
    } else {
        int bh = (blockIdx.x - 32) * 4 + (t >> 6);
        int d = t & 63;
        float s = 0.f;
        #pragma unroll
        for (int c = 0; c < 16; ++c) s += Vpart[(bh * 16 + c) * 64 + d];
        mean[bh * 64 + d] = s * (1.0f / (float)L);
    }
}

// ================= K_C: split-K selected attention (blocks [0, B*H*NCC)) + fill (next 2048)
// Fixed-shift softmax: e = exp(s*0.125 - 16), shift-invariant.
template <int CC>
__global__ __launch_bounds__(256, 4) void kC(const float* __restrict__ Q, const float* __restrict__ K,
                                             const float* __restrict__ V, const int* __restrict__ Mtop,
                                             const float* __restrict__ mean, float* __restrict__ Npart,
                                             float* __restrict__ Zpart, float* __restrict__ out) {
    constexpr int NCC = L / CC;
    constexpr int KPT = CC / 32;                       // keys per thread in score phase
    constexpr int LDK = CC + (KPT == 4 ? 4 : 2);       // K^T row stride
    constexpr int LDP = LDK;
    constexpr int LDV = 68;
    constexpr int KVSZ = (CC * LDV > 64 * LDK) ? CC * LDV : 64 * LDK;
    constexpr int VPT = CC * 16 / 256;                 // V float4 loads per thread (CC=64 -> 4)
    __shared__ float KV[KVSZ];
    __shared__ float Qs[TOP * 64];
    __shared__ float Ps[TOP * LDP];
    const int t = threadIdx.x;
    const int nsel = B * H * NCC;
    if (blockIdx.x >= nsel) {
        // ---- broadcast-fill context with mean ----
        const int N4 = B * H * L * D / 4;
        const float4* m4 = (const float4*)mean;
        float4* o4 = (float4*)out;
        for (int i = (blockIdx.x - nsel) * 256 + t; i < N4; i += 2048 * 256) {
            int bh = i >> 15, d4 = i & 15;
            o4[i] = m4[bh * 16 + d4];
        }
        return;
    }
    const int bh = blockIdx.x / NCC, kc = blockIdx.x % NCC;
    const int b = bh >> 3, h = bh & 7;
    const int k0 = kc * CC;
    // stage K^T and Q together, single barrier
    for (int i = t; i < CC * 16; i += 256) {
        int kk = i >> 4, d4 = i & 15;
        float4 kv = *(const float4*)&K[(((b * L + k0 + kk) * H + h) << 6) + d4 * 4];
        KV[(d4 * 4 + 0) * LDK + kk] = kv.x;
        KV[(d4 * 4 + 1) * LDK + kk] = kv.y;
        KV[(d4 * 4 + 2) * LDK + kk] = kv.z;
        KV[(d4 * 4 + 3) * LDK + kk] = kv.w;
    }
    for (int i = t; i < TOP * 16; i += 256) {
        int u = i >> 4, d4 = i & 15;
        int lsel = Mtop[bh * TOP + u];                 // L2-hot broadcast load
        *(float4*)&Qs[u * 64 + d4 * 4] =
            *(const float4*)&Q[(((b * L + lsel) * H + h) << 6) + d4 * 4];
    }
    // ---- prefetch V into registers (T14): loads fly during score phase ----
    float4 vpre[VPT];
    #pragma unroll
    for (int p = 0; p < VPT; ++p) {
        int i = p * 256 + t;
        int kk = i >> 4, d4 = i & 15;
        vpre[p] = *(const float4*)&V[(((b * L + k0 + kk) * H + h) << 6) + d4 * 4];
    }
    __syncthreads();
    // scores: thread owns KPT keys (k2*KPT..) x 5 queries (ug*5..)
    const int k2 = t & 31, ug = t >> 5;
    float acc[5][KPT];
    #pragma unroll
    for (int j = 0; j < 5; ++j)
        #pragma unroll
        for (int p = 0; p < KPT; ++p) acc[j][p] = 0.f;
    #pragma unroll 4
    for (int d4 = 0; d4 < 16; ++d4) {
        float kr[4][KPT];
        #pragma unroll
        for (int rr = 0; rr < 4; ++rr)
            #pragma unroll
            for (int p = 0; p < KPT; ++p)
                kr[rr][p] = KV[(d4 * 4 + rr) * LDK + k2 * KPT + p];
        #pragma unroll
        for (int j = 0; j < 5; ++j) {
            float4 q4 = *(const float4*)&Qs[(ug * 5 + j) * 64 + d4 * 4];
            #pragma unroll
            for (int p = 0; p < KPT; ++p)
                acc[j][p] += q4.x * kr[0][p] + q4.y * kr[1][p] + q4.z * kr[2][p] + q4.w * kr[3][p];
        }
    }
    #pragma unroll
    for (int j = 0; j < 5; ++j) {
        int u = ug * 5 + j;
        float z = 0.f;
        #pragma unroll
        for (int p = 0; p < KPT; ++p) {
            float e = __expf(acc[j][p] * 0.125f - 16.0f);
            Ps[u * LDP + k2 * KPT + p] = e;
            z += e;
        }
        z += __shfl_xor(z, 1); z += __shfl_xor(z, 2); z += __shfl_xor(z, 4);
        z += __shfl_xor(z, 8); z += __shfl_xor(z, 16);
        if (k2 == 0) Zpart[(bh * TOP + u) * NCC + kc] = z;
    }
    __syncthreads();
    // write prefetched V row-major over K^T space
    #pragma unroll
    for (int p = 0; p < VPT; ++p) {
        int i = p * 256 + t;
        int kk = i >> 4, d4 = i & 15;
        *(float4*)&KV[kk * LDV + d4 * 4] = vpre[p];
    }
    __syncthreads();
    // PV: thread owns d4v (4 dims) x queries {ug2, ug2+16, ug2+32(<40)}
    const int d4v = t & 15, ug2 = t >> 4;
    float4 o0 = make_float4(0,0,0,0), o1 = make_float4(0,0,0,0), o2 = make_float4(0,0,0,0);
    #pragma unroll 4
    for (int kk = 0; kk < CC; ++kk) {
        float4 vv = *(const float4*)&KV[kk * LDV + d4v * 4];
        float e0 = Ps[ug2 * LDP + kk];
        float e1 = Ps[(ug2 + 16) * LDP + kk];
        o0.x += e0 * vv.x; o0.y += e0 * vv.y; o0.z += e0 * vv.z; o0.w += e0 * vv.w;
        o1.x += e1 * vv.x; o1.y += e1 * vv.y; o1.z += e1 * vv.z; o1.w += e1 * vv.w;
        if (ug2 < 8) {                        // wave-uniform branch
            float e2 = Ps[(ug2 + 32) * LDP + kk];
            o2.x += e2 * vv.x; o2.y += e2 * vv.y; o2.z += e2 * vv.z; o2.w += e2 * vv.w;
        }
    }
    *(float4*)&Npart[((bh * TOP + ug2) * NCC + kc) * 64 + d4v * 4] = o0;
    *(float4*)&Npart[((bh * TOP + ug2 + 16) * NCC + kc) * 64 + d4v * 4] = o1;
    if (ug2 < 8)
        *(float4*)&Npart[((bh * TOP + ug2 + 32) * NCC + kc) * 64 + d4v * 4] = o2;
}

// ================= K_D: combine partials + scatter ==================
template <int NCC>
__global__ __launch_bounds__(256) void kD(const int* __restrict__ Mtop, const float* __restrict__ Npart,
                                          const float* __restrict__ Zpart, float* __restrict__ out) {
    const int t = threadIdx.x;
    const int g = blockIdx.x * 4 + (t >> 6);   // (bh,u) flat in [0,1280)
    const int d = t & 63;
    const int bh = g / TOP;
    const int lsel = Mtop[g];
    float z = 0.f;
    #pragma unroll
    for (int c = 0; c < NCC; ++c) z += Zpart[g * NCC + c];
    float n = 0.f;
    #pragma unroll
    for (int c = 0; c < NCC; ++c) n += Npart[(g * NCC + c) * 64 + d];
    out[((bh * L + lsel) << 6) + d] = n / z;
}

// ================= tier-3 fallback (tiny ws): fused per-query attention + fill ==========
__global__ void fill_ctx(const float* __restrict__ mean, float4* __restrict__ out) {
    const int N4 = B * H * L * D / 4;
    for (int i = blockIdx.x * 256 + threadIdx.x; i < N4; i += gridDim.x * 256) {
        int bh = i >> 15, d4 = i & 15;
        out[i] = ((const float4*)mean)[bh * 16 + d4];
    }
}
__global__ void sel_attn(const float* __restrict__ Q, const float* __restrict__ K,
                         const float* __restrict__ V, const int* __restrict__ Mtop,
                         float* __restrict__ out) {
    __shared__ float qs[D];
    __shared__ float p[L];
    __shared__ float red[256];
    int blk = blockIdx.x;
    int bh = blk / TOP, u = blk - bh * TOP;
    int b = bh >> 3, h = bh & 7;
    int t = threadIdx.x;
    int lsel = Mtop[bh * TOP + u];
    if (t < 64) qs[t] = Q[(((b * L + lsel) * H + h) << 6) + t];
    __syncthreads();
    float lsum = 0.f;
    for (int kk = 0; kk < 8; ++kk) {
        int k = kk * 256 + t;
        const float4* krow = (const float4*)&K[((b * L + k) * H + h) << 6];
        const float4* q4 = (const float4*)qs;
        float acc = 0.f;
        #pragma unroll
        for (int j = 0; j < 16; ++j) {
            float4 kv = krow[j]; float4 qv = q4[j];
            acc += qv.x * kv.x + qv.y * kv.y + qv.z * kv.z + qv.w * kv.w;
        }
        float e = __expf(acc * 0.125f - 16.0f);
        p[k] = e;
        lsum += e;
    }
    red[t] = lsum; __syncthreads();
    for (int off = 128; off > 0; off >>= 1) {
        if (t < off) red[t] += red[t + off];
        __syncthreads();
    }
    float inv = 1.0f / red[0];
    __syncthreads();
    int d = t & 63, c = t >> 6;
    float acc = 0.f;
    for (int k = c * 512; k < (c + 1) * 512; ++k)
        acc += p[k] * V[(((b * L + k) * H + h) << 6) + d];
    red[t] = acc; __syncthreads();
    if (t < 128) red[t] += red[t + 128];
    __syncthreads();
    if (t < 64) out[((bh * L + lsel) << 6) + t] = (red[t] + red[t + 64]) * inv;
}

extern "C" void kernel_launch(void* const* d_in, const int* in_sizes, int n_in,
                              void* d_out, int out_size, void* d_ws, size_t ws_size,
                              hipStream_t stream) {
    const float* Q = (const float*)d_in[0];
    const float* K = (const float*)d_in[1];
    const float* V = (const float*)d_in[2];
    const int* idx = (const int*)d_in[4];
    float* out = (float*)d_out;

    // --- ws layout ---
    // phase-1 (kA/kB): M at [0, 262144)
    // phase-2 (kC/kD): Zpart at [0, 163840), Npart at [163840, +npb)  (overlays dead M)
    // persistent:      Mtop / mean / Vpart after max(Npart end, 262144)
    char* ws = (char*)d_ws;
    const size_t NPB1 = (size_t)B * H * TOP * 32 * 64 * 4;   // NCC=32: 10,485,760
    const size_t NPB2 = (size_t)B * H * TOP * 16 * 64 * 4;   // NCC=16:  5,242,880
    auto layout = [&](size_t npb, size_t& persist) {
        size_t e = 163840 + npb;
        persist = (e > 262144 ? e : 262144);
        return persist + 5120 + 8192 + 131072 + 3072;        // Mtop+mean+Vpart (+pad)
    };
    size_t p1, p2, p3;
    size_t need1 = layout(NPB1, p1);
    size_t need2 = layout(NPB2, p2);
    size_t need3 = layout(0, p3);
    int tier = (ws_size >= need1) ? 1 : (ws_size >= need2) ? 2 : (ws_size >= need3) ? 3 : 0;
    size_t persist = (tier == 1) ? p1 : (tier == 2) ? p2 : p3;

    float* M     = (float*)ws;
    float* Zpart = (float*)ws;
    float* Npart = (float*)(ws + 163840);
    int*   Mtop  = (int*)(ws + persist);
    float* mean  = (float*)(ws + persist + 5120);
    float* Vpart = (float*)(ws + persist + 5120 + 8192);

    kA<<<NMB + 512, 256, 0, stream>>>(Q, K, V, idx, M, Vpart);
    kB<<<40, 256, 0, stream>>>(M, Vpart, Mtop, mean);
    if (tier == 1) {
        kC<64><<<B * H * 32 + 2048, 256, 0, stream>>>(Q, K, V, Mtop, mean, Npart, Zpart, out);
        kD<32><<<320, 256, 0, stream>>>(Mtop, Npart, Zpart, out);
    } else if (tier == 2) {
        kC<128><<<B * H * 16 + 2048, 256, 0, stream>>>(Q, K, V, Mtop, mean, Npart, Zpart, out);
        kD<16><<<320, 256, 0, stream>>>(Mtop, Npart, Zpart, out);
    } else {
        fill_ctx<<<2048, 256, 0, stream>>>(mean, (float4*)out);
        sel_attn<<<B * H * TOP, 256, 0, stream>>>(Q, K, V, Mtop, out);
    }
}

// Round 19
// 109.044 us; speedup vs baseline: 1.0968x; 1.0968x over previous
//
#include <hip/hip_runtime.h>
#include <hip/hip_bf16.h>

// ProbSparse attention (Informer). B=4, L=2048, H=8, D=64, S=TOP=40.
constexpr int B = 4, L = 2048, H = 8, D = 64, S = 40, TOP = 40;
constexpr int NMB = B * L;           // 8192 M-blocks: one (b,l) each, all 8 heads

// ================= K_A: compute_M (blocks 0..NMB-1) + vmean partials (next 512) ==========
// (b,l)-centric gather: K[b,ki,:,:] is a contiguous 2KB block covering ALL 8 heads; sample
// indices depend only on l -> one coalesced gather serves 8 heads. ~44us = L2 gather-rate
// ceiling (invariant across 7 access-pattern/depth/occupancy variants, r5-r18).
// NOTE: 4 blocks/CU is the L2-capacity sweet spot; 8 blocks/CU doubles FETCH (r18).
__global__ __launch_bounds__(256, 4) void kA(const float* __restrict__ Q, const float* __restrict__ K,
                                             const float* __restrict__ V, const int* __restrict__ idx,
                                             float* __restrict__ M, float* __restrict__ Vpart) {
    __shared__ float4 red[256];
    __shared__ float wmax[4][8], wsum[4][8];
    const int t = threadIdx.x;
    if (blockIdx.x < NMB) {
        int n = blockIdx.x;
        int b = n & 3;                                   // xcd = n&7 pins b to 2 XCDs
        int l = ((n >> 2) & 1) * 1024 + (n >> 3);
        int lane = t & 63, w = t >> 6;
        const float* Qb = Q + ((size_t)(b * L + l) << 9);
        const float* Kb = K + ((size_t)(b * L) << 9);
        float4 qa = *(const float4*)(Qb + lane * 4);          // heads 0-3
        float4 qb = *(const float4*)(Qb + 256 + lane * 4);    // heads 4-7
        int ki[10];
        #pragma unroll
        for (int i = 0; i < 10; ++i) ki[i] = idx[l * S + w * 10 + i];   // wave-uniform
        float4 ka[10], kb[10];
        #pragma unroll
        for (int i = 0; i < 10; ++i) {
            const float* kr = Kb + ((size_t)ki[i] << 9);
            ka[i] = *(const float4*)(kr + lane * 4);          // coalesced 1KB per load
            kb[i] = *(const float4*)(kr + 256 + lane * 4);
        }
        float maxa = -3.4e38f, suma = 0.f, maxb = -3.4e38f, sumb = 0.f;
        #pragma unroll
        for (int i = 0; i < 10; ++i) {
            float pa = qa.x * ka[i].x + qa.y * ka[i].y + qa.z * ka[i].z + qa.w * ka[i].w;
            float pb = qb.x * kb[i].x + qb.y * kb[i].y + qb.z * kb[i].z + qb.w * kb[i].w;
            pa += __shfl_xor(pa, 1); pa += __shfl_xor(pa, 2);
            pa += __shfl_xor(pa, 4); pa += __shfl_xor(pa, 8);
            pb += __shfl_xor(pb, 1); pb += __shfl_xor(pb, 2);
            pb += __shfl_xor(pb, 4); pb += __shfl_xor(pb, 8);
            maxa = fmaxf(maxa, pa); suma += pa;
            maxb = fmaxf(maxb, pb); sumb += pb;
        }
        if ((lane & 15) == 0) {
            int g = lane >> 4;
            wmax[w][g] = maxa;     wsum[w][g] = suma;
            wmax[w][g + 4] = maxb; wsum[w][g + 4] = sumb;
        }
        __syncthreads();
        if (t < 8) {
            float mv = wmax[0][t], sv = wsum[0][t];
            #pragma unroll
            for (int ww = 1; ww < 4; ++ww) { mv = fmaxf(mv, wmax[ww][t]); sv += wsum[ww][t]; }
            M[(b * 8 + t) * L + l] = mv - sv * (1.0f / (float)L);
        }
    } else {
        // ---- V mean partials: 512 blocks ----
        int m = blockIdx.x - NMB;                       // NMB % 8 == 0
        int xcd = m & 7, slot = m >> 3;                 // slot in [0,64)
        int bh = xcd * 4 + (slot & 3);
        int chunk = slot >> 2;                          // [0,16)
        int b = bh >> 3, h = bh & 7;
        int d4 = t & 15, rr = t >> 4;
        int l0 = chunk * 128;
        float4 acc = make_float4(0.f, 0.f, 0.f, 0.f);
        #pragma unroll
        for (int s = 0; s < 8; ++s) {
            int l = l0 + rr + s * 16;
            float4 v = *(const float4*)&V[(((b * L + l) * H + h) << 6) + d4 * 4];
            acc.x += v.x; acc.y += v.y; acc.z += v.z; acc.w += v.w;
        }
        red[t] = acc;
        __syncthreads();
        #pragma unroll
        for (int off = 8; off > 0; off >>= 1) {
            if (rr < off) {
                float4 o = red[t + off * 16];
                red[t].x += o.x; red[t].y += o.y; red[t].z += o.z; red[t].w += o.w;
            }
            __syncthreads();
        }
        if (rr == 0) *(float4*)&Vpart[(bh * 16 + chunk) * 64 + d4 * 4] = red[t];
    }
}

// ================= K_B: top-40 (blocks 0..31, one per bh, 8 vals/thread in regs)
//                        + mean finalize (blocks 32..39) =============================
__global__ __launch_bounds__(256) void kB(const float* __restrict__ M, const float* __restrict__ Vpart,
                                          int* __restrict__ Mtop, float* __restrict__ mean) {
    const int t = threadIdx.x;
    if (blockIdx.x < 32) {
        const int bh = blockIdx.x;
        const int lane = t & 63, wid = t >> 6;
        float v[8];                               // 8 regs, statically indexed everywhere
        #pragma unroll
        for (int j = 0; j < 8; ++j) v[j] = M[bh * L + j * 256 + t];
        float bv = v[0]; int bj = 0;              // cached per-thread argmax
        #pragma unroll
        for (int j = 1; j < 8; ++j) if (v[j] > bv) { bv = v[j]; bj = j; }
        __shared__ float swv[4];
        __shared__ int   swi[4];
        __shared__ int   winS;
        for (int it = 0; it < TOP; ++it) {
            float cv = bv; int ci = bj * 256 + t;      // global index l = j*256 + t
            #pragma unroll
            for (int m = 1; m < 64; m <<= 1) {
                float ov = __shfl_xor(cv, m); int oi = __shfl_xor(ci, m);
                if (ov > cv || (ov == cv && oi < ci)) { cv = ov; ci = oi; }
            }
            if (lane == 0) { swv[wid] = cv; swi[wid] = ci; }
            __syncthreads();
            if (t == 0) {
                float fv = swv[0]; int fi = swi[0];
                #pragma unroll
                for (int w = 1; w < 4; ++w)
                    if (swv[w] > fv || (swv[w] == fv && swi[w] < fi)) { fv = swv[w]; fi = swi[w]; }
                Mtop[bh * TOP + it] = fi;
                winS = fi;
            }
            __syncthreads();
            const int wl = winS;
            if ((wl & 255) == t) {                 // owner thread: kill + rescan 8 (static)
                if ((wl >> 8) == 0) v[0] = -3.4e38f;
                if ((wl >> 8) == 1) v[1] = -3.4e38f;
                if ((wl >> 8) == 2) v[2] = -3.4e38f;
                if ((wl >> 8) == 3) v[3] = -3.4e38f;
                if ((wl >> 8) == 4) v[4] = -3.4e38f;
                if ((wl >> 8) == 5) v[5] = -3.4e38f;
                if ((wl >> 8) == 6) v[6] = -3.4e38f;
                if ((wl >> 8) == 7) v[7] = -3.4e38f;
                bv = v[0]; bj = 0;
                #pragma unroll
                for (int j = 1; j < 8; ++j) if (v[j] > bv) { bv = v[j]; bj = j; }
            }
        }
    } else {
        int bh = (blockIdx.x - 32) * 4 + (t >> 6);
        int d = t & 63;
        float s = 0.f;
        #pragma unroll
        for (int c = 0; c < 16; ++c) s += Vpart[(bh * 16 + c) * 64 + d];
        mean[bh * 64 + d] = s * (1.0f / (float)L);
    }
}

// ================= K_C: split-K selected attention (blocks [0, B*H*NCC)) + fill (next 2048)
// Fixed-shift softmax: e = exp(s*0.125 - 16), shift-invariant.
template <int CC>
__global__ __launch_bounds__(256, 4) void kC(const float* __restrict__ Q, const float* __restrict__ K,
                                             const float* __restrict__ V, const int* __restrict__ Mtop,
                                             const float* __restrict__ mean, float* __restrict__ Npart,
                                             float* __restrict__ Zpart, float* __restrict__ out) {
    constexpr int NCC = L / CC;
    constexpr int KPT = CC / 32;                       // keys per thread in score phase
    constexpr int LDK = CC + (KPT == 4 ? 4 : 2);       // K^T row stride
    constexpr int LDP = LDK;
    constexpr int LDV = 68;
    constexpr int KVSZ = (CC * LDV > 64 * LDK) ? CC * LDV : 64 * LDK;
    constexpr int VPT = CC * 16 / 256;                 // V float4 loads per thread (CC=64 -> 4)
    __shared__ float KV[KVSZ];
    __shared__ float Qs[TOP * 64];
    __shared__ float Ps[TOP * LDP];
    const int t = threadIdx.x;
    const int nsel = B * H * NCC;
    if (blockIdx.x >= nsel) {
        // ---- broadcast-fill context with mean ----
        const int N4 = B * H * L * D / 4;
        const float4* m4 = (const float4*)mean;
        float4* o4 = (float4*)out;
        for (int i = (blockIdx.x - nsel) * 256 + t; i < N4; i += 2048 * 256) {
            int bh = i >> 15, d4 = i & 15;
            o4[i] = m4[bh * 16 + d4];
        }
        return;
    }
    const int bh = blockIdx.x / NCC, kc = blockIdx.x % NCC;
    const int b = bh >> 3, h = bh & 7;
    const int k0 = kc * CC;
    // stage K^T and Q together, single barrier
    for (int i = t; i < CC * 16; i += 256) {
        int kk = i >> 4, d4 = i & 15;
        float4 kv = *(const float4*)&K[(((b * L + k0 + kk) * H + h) << 6) + d4 * 4];
        KV[(d4 * 4 + 0) * LDK + kk] = kv.x;
        KV[(d4 * 4 + 1) * LDK + kk] = kv.y;
        KV[(d4 * 4 + 2) * LDK + kk] = kv.z;
        KV[(d4 * 4 + 3) * LDK + kk] = kv.w;
    }
    for (int i = t; i < TOP * 16; i += 256) {
        int u = i >> 4, d4 = i & 15;
        int lsel = Mtop[bh * TOP + u];                 // L2-hot broadcast load
        *(float4*)&Qs[u * 64 + d4 * 4] =
            *(const float4*)&Q[(((b * L + lsel) * H + h) << 6) + d4 * 4];
    }
    // ---- prefetch V into registers (T14): loads fly during score phase ----
    float4 vpre[VPT];
    #pragma unroll
    for (int p = 0; p < VPT; ++p) {
        int i = p * 256 + t;
        int kk = i >> 4, d4 = i & 15;
        vpre[p] = *(const float4*)&V[(((b * L + k0 + kk) * H + h) << 6) + d4 * 4];
    }
    __syncthreads();
    // scores: thread owns KPT keys (k2*KPT..) x 5 queries (ug*5..)
    const int k2 = t & 31, ug = t >> 5;
    float acc[5][KPT];
    #pragma unroll
    for (int j = 0; j < 5; ++j)
        #pragma unroll
        for (int p = 0; p < KPT; ++p) acc[j][p] = 0.f;
    #pragma unroll 4
    for (int d4 = 0; d4 < 16; ++d4) {
        float kr[4][KPT];
        #pragma unroll
        for (int rr = 0; rr < 4; ++rr)
            #pragma unroll
            for (int p = 0; p < KPT; ++p)
                kr[rr][p] = KV[(d4 * 4 + rr) * LDK + k2 * KPT + p];
        #pragma unroll
        for (int j = 0; j < 5; ++j) {
            float4 q4 = *(const float4*)&Qs[(ug * 5 + j) * 64 + d4 * 4];
            #pragma unroll
            for (int p = 0; p < KPT; ++p)
                acc[j][p] += q4.x * kr[0][p] + q4.y * kr[1][p] + q4.z * kr[2][p] + q4.w * kr[3][p];
        }
    }
    #pragma unroll
    for (int j = 0; j < 5; ++j) {
        int u = ug * 5 + j;
        float z = 0.f;
        #pragma unroll
        for (int p = 0; p < KPT; ++p) {
            float e = __expf(acc[j][p] * 0.125f - 16.0f);
            Ps[u * LDP + k2 * KPT + p] = e;
            z += e;
        }
        z += __shfl_xor(z, 1); z += __shfl_xor(z, 2); z += __shfl_xor(z, 4);
        z += __shfl_xor(z, 8); z += __shfl_xor(z, 16);
        if (k2 == 0) Zpart[(bh * TOP + u) * NCC + kc] = z;
    }
    __syncthreads();
    // write prefetched V row-major over K^T space
    #pragma unroll
    for (int p = 0; p < VPT; ++p) {
        int i = p * 256 + t;
        int kk = i >> 4, d4 = i & 15;
        *(float4*)&KV[kk * LDV + d4 * 4] = vpre[p];
    }
    __syncthreads();
    // PV: thread owns d4v (4 dims) x queries {ug2, ug2+16, ug2+32(<40)}
    const int d4v = t & 15, ug2 = t >> 4;
    float4 o0 = make_float4(0,0,0,0), o1 = make_float4(0,0,0,0), o2 = make_float4(0,0,0,0);
    #pragma unroll 4
    for (int kk = 0; kk < CC; ++kk) {
        float4 vv = *(const float4*)&KV[kk * LDV + d4v * 4];
        float e0 = Ps[ug2 * LDP + kk];
        float e1 = Ps[(ug2 + 16) * LDP + kk];
        o0.x += e0 * vv.x; o0.y += e0 * vv.y; o0.z += e0 * vv.z; o0.w += e0 * vv.w;
        o1.x += e1 * vv.x; o1.y += e1 * vv.y; o1.z += e1 * vv.z; o1.w += e1 * vv.w;
        if (ug2 < 8) {                        // wave-uniform branch
            float e2 = Ps[(ug2 + 32) * LDP + kk];
            o2.x += e2 * vv.x; o2.y += e2 * vv.y; o2.z += e2 * vv.z; o2.w += e2 * vv.w;
        }
    }
    *(float4*)&Npart[((bh * TOP + ug2) * NCC + kc) * 64 + d4v * 4] = o0;
    *(float4*)&Npart[((bh * TOP + ug2 + 16) * NCC + kc) * 64 + d4v * 4] = o1;
    if (ug2 < 8)
        *(float4*)&Npart[((bh * TOP + ug2 + 32) * NCC + kc) * 64 + d4v * 4] = o2;
}

// ================= K_D: combine partials + scatter ==================
template <int NCC>
__global__ __launch_bounds__(256) void kD(const int* __restrict__ Mtop, const float* __restrict__ Npart,
                                          const float* __restrict__ Zpart, float* __restrict__ out) {
    const int t = threadIdx.x;
    const int g = blockIdx.x * 4 + (t >> 6);   // (bh,u) flat in [0,1280)
    const int d = t & 63;
    const int bh = g / TOP;
    const int lsel = Mtop[g];
    float z = 0.f;
    #pragma unroll
    for (int c = 0; c < NCC; ++c) z += Zpart[g * NCC + c];
    float n = 0.f;
    #pragma unroll
    for (int c = 0; c < NCC; ++c) n += Npart[(g * NCC + c) * 64 + d];
    out[((bh * L + lsel) << 6) + d] = n / z;
}

// ================= tier-3 fallback (tiny ws): fused per-query attention + fill ==========
__global__ void fill_ctx(const float* __restrict__ mean, float4* __restrict__ out) {
    const int N4 = B * H * L * D / 4;
    for (int i = blockIdx.x * 256 + threadIdx.x; i < N4; i += gridDim.x * 256) {
        int bh = i >> 15, d4 = i & 15;
        out[i] = ((const float4*)mean)[bh * 16 + d4];
    }
}
__global__ void sel_attn(const float* __restrict__ Q, const float* __restrict__ K,
                         const float* __restrict__ V, const int* __restrict__ Mtop,
                         float* __restrict__ out) {
    __shared__ float qs[D];
    __shared__ float p[L];
    __shared__ float red[256];
    int blk = blockIdx.x;
    int bh = blk / TOP, u = blk - bh * TOP;
    int b = bh >> 3, h = bh & 7;
    int t = threadIdx.x;
    int lsel = Mtop[bh * TOP + u];
    if (t < 64) qs[t] = Q[(((b * L + lsel) * H + h) << 6) + t];
    __syncthreads();
    float lsum = 0.f;
    for (int kk = 0; kk < 8; ++kk) {
        int k = kk * 256 + t;
        const float4* krow = (const float4*)&K[((b * L + k) * H + h) << 6];
        const float4* q4 = (const float4*)qs;
        float acc = 0.f;
        #pragma unroll
        for (int j = 0; j < 16; ++j) {
            float4 kv = krow[j]; float4 qv = q4[j];
            acc += qv.x * kv.x + qv.y * kv.y + qv.z * kv.z + qv.w * kv.w;
        }
        float e = __expf(acc * 0.125f - 16.0f);
        p[k] = e;
        lsum += e;
    }
    red[t] = lsum; __syncthreads();
    for (int off = 128; off > 0; off >>= 1) {
        if (t < off) red[t] += red[t + off];
        __syncthreads();
    }
    float inv = 1.0f / red[0];
    __syncthreads();
    int d = t & 63, c = t >> 6;
    float acc = 0.f;
    for (int k = c * 512; k < (c + 1) * 512; ++k)
        acc += p[k] * V[(((b * L + k) * H + h) << 6) + d];
    red[t] = acc; __syncthreads();
    if (t < 128) red[t] += red[t + 128];
    __syncthreads();
    if (t < 64) out[((bh * L + lsel) << 6) + t] = (red[t] + red[t + 64]) * inv;
}

extern "C" void kernel_launch(void* const* d_in, const int* in_sizes, int n_in,
                              void* d_out, int out_size, void* d_ws, size_t ws_size,
                              hipStream_t stream) {
    const float* Q = (const float*)d_in[0];
    const float* K = (const float*)d_in[1];
    const float* V = (const float*)d_in[2];
    const int* idx = (const int*)d_in[4];
    float* out = (float*)d_out;

    // --- ws layout ---
    // phase-1 (kA/kB): M at [0, 262144)
    // phase-2 (kC/kD): Zpart at [0, 163840), Npart at [163840, +npb)  (overlays dead M)
    // persistent:      Mtop / mean / Vpart after max(Npart end, 262144)
    char* ws = (char*)d_ws;
    const size_t NPB1 = (size_t)B * H * TOP * 32 * 64 * 4;   // NCC=32: 10,485,760
    const size_t NPB2 = (size_t)B * H * TOP * 16 * 64 * 4;   // NCC=16:  5,242,880
    auto layout = [&](size_t npb, size_t& persist) {
        size_t e = 163840 + npb;
        persist = (e > 262144 ? e : 262144);
        return persist + 5120 + 8192 + 131072 + 3072;        // Mtop+mean+Vpart (+pad)
    };
    size_t p1, p2, p3;
    size_t need1 = layout(NPB1, p1);
    size_t need2 = layout(NPB2, p2);
    size_t need3 = layout(0, p3);
    int tier = (ws_size >= need1) ? 1 : (ws_size >= need2) ? 2 : (ws_size >= need3) ? 3 : 0;
    size_t persist = (tier == 1) ? p1 : (tier == 2) ? p2 : p3;

    float* M     = (float*)ws;
    float* Zpart = (float*)ws;
    float* Npart = (float*)(ws + 163840);
    int*   Mtop  = (int*)(ws + persist);
    float* mean  = (float*)(ws + persist + 5120);
    float* Vpart = (float*)(ws + persist + 5120 + 8192);

    kA<<<NMB + 512, 256, 0, stream>>>(Q, K, V, idx, M, Vpart);
    kB<<<40, 256, 0, stream>>>(M, Vpart, Mtop, mean);
    if (tier == 1) {
        kC<64><<<B * H * 32 + 2048, 256, 0, stream>>>(Q, K, V, Mtop, mean, Npart, Zpart, out);
        kD<32><<<320, 256, 0, stream>>>(Mtop, Npart, Zpart, out);
    } else if (tier == 2) {
        kC<128><<<B * H * 16 + 2048, 256, 0, stream>>>(Q, K, V, Mtop, mean, Npart, Zpart, out);
        kD<16><<<320, 256, 0, stream>>>(Mtop, Npart, Zpart, out);
    } else {
        fill_ctx<<<2048, 256, 0, stream>>>(mean, (float4*)out);
        sel_attn<<<B * H * TOP, 256, 0, stream>>>(Q, K, V, Mtop, out);
    }
}